// Round 3
// baseline (4320.106 us; speedup 1.0000x reference)
//
#include <hip/hip_runtime.h>
#include <math.h>

#define N_NODES 20000
#define N_EDGES 320000
#define T_STEPS 16
#define TB 8                       // timesteps per half-batch
#define RB_ROWS (N_NODES * TB)     // 160000 rows = 1250 * 128
#define F_INDIM 128
#define HC 256
#define HEADS 4
#define CDIM 64
#define G3 192
#define EPN (N_EDGES + N_NODES)    // 340000 edges incl self-loops per t

// ---------------- CSR build (all 16 timesteps in 4 launches) ----------------

__global__ void k_csr_init(int* __restrict__ cnt) {
    int i = blockIdx.x * 256 + threadIdx.x;
    if (i < T_STEPS * N_NODES) cnt[i] = 1;   // self-loop
}

__global__ void k_csr_count(const int* __restrict__ ei, int* __restrict__ cnt_all) {
    int t = blockIdx.y;
    int i = blockIdx.x * 256 + threadIdx.x;
    if (i < N_EDGES)
        atomicAdd(&cnt_all[t * N_NODES + ei[(size_t)t * 2 * N_EDGES + N_EDGES + i]], 1);
}

__global__ __launch_bounds__(1024) void k_csr_scan(const int* __restrict__ cnt_all,
                                                   int* __restrict__ off_all,
                                                   int* __restrict__ cur_all) {
    __shared__ int sdata[1024];
    const int t = blockIdx.x;
    const int* cnt = cnt_all + t * N_NODES;
    int* off = off_all + t * (N_NODES + 1);
    int* cur = cur_all + t * N_NODES;
    int tid = threadIdx.x;
    const int ITEMS = (N_NODES + 1023) / 1024;   // 20
    int start = tid * ITEMS;
    int local = 0;
    for (int i = 0; i < ITEMS; ++i) {
        int idx = start + i;
        if (idx < N_NODES) local += cnt[idx];
    }
    sdata[tid] = local;
    __syncthreads();
    for (int s = 1; s < 1024; s <<= 1) {
        int v = (tid >= s) ? sdata[tid - s] : 0;
        __syncthreads();
        sdata[tid] += v;
        __syncthreads();
    }
    int run = sdata[tid] - local;   // exclusive
    for (int i = 0; i < ITEMS; ++i) {
        int idx = start + i;
        if (idx < N_NODES) {
            off[idx] = run;
            cur[idx] = run;
            run += cnt[idx];
        }
    }
    if (tid == 0) off[N_NODES] = EPN;
}

__global__ void k_csr_fill(const int* __restrict__ ei, int* __restrict__ cur_all,
                           int* __restrict__ csr_all) {
    int t = blockIdx.y;
    int i = blockIdx.x * 256 + threadIdx.x;
    int* cur = cur_all + t * N_NODES;
    int* csr = csr_all + (size_t)t * EPN;
    const int* e = ei + (size_t)t * 2 * N_EDGES;
    if (i < N_EDGES) {
        int s = e[i], d = e[N_EDGES + i];
        csr[atomicAdd(&cur[d], 1)] = s;
    } else if (i < EPN) {
        int d = i - N_EDGES;
        csr[atomicAdd(&cur[d], 1)] = d;
    }
}

// ---------------- GEMM: C[RB_ROWS x 256] = A[RB_ROWS x K] * B[K x 256] ----------------
// 128x128 tile, 256 threads, 8x8 per thread, BK=16.
// Row l is (tl, s) with tl = l / N_NODES, s = l % N_NODES (slice-major).
// XMAP: A row l reads x_sequence row s*T_STEPS + tbase + tl, lda = 128.

template <bool XMAP>
__global__ __launch_bounds__(256) void k_gemm(const float* __restrict__ A, int lda,
                                              const float* __restrict__ B, int ldb,
                                              float* __restrict__ C, int ldc,
                                              int K, int tbase) {
    __shared__ __align__(16) float As[16][132];
    __shared__ __align__(16) float Bs[16][128];
    const int tid = threadIdx.x;
    const int row0 = blockIdx.y * 128;
    const int col0 = blockIdx.x * 128;
    const int tx = tid & 15, ty = tid >> 4;
    float acc[8][8] = {};

    const int arow = tid >> 2;        // 0..63
    const int akq  = tid & 3;         // float4 index along k
    const int bcol = (tid & 31) * 4;
    const int bk   = tid >> 5;        // 0..7

    for (int kk = 0; kk < K; kk += 16) {
#pragma unroll
        for (int p = 0; p < 2; ++p) {
            int l = row0 + arow + 64 * p;
            int rg;
            if (XMAP) {
                int tl = l / N_NODES;
                int s = l - tl * N_NODES;
                rg = s * T_STEPS + tbase + tl;
            } else {
                rg = l;
            }
            const float4 v = *(const float4*)&A[(size_t)rg * lda + kk + akq * 4];
            As[akq * 4 + 0][arow + 64 * p] = v.x;
            As[akq * 4 + 1][arow + 64 * p] = v.y;
            As[akq * 4 + 2][arow + 64 * p] = v.z;
            As[akq * 4 + 3][arow + 64 * p] = v.w;
        }
#pragma unroll
        for (int p = 0; p < 2; ++p) {
            int k = bk + 8 * p;
            *(float4*)&Bs[k][bcol] = *(const float4*)&B[(size_t)(kk + k) * ldb + col0 + bcol];
        }
        __syncthreads();
#pragma unroll
        for (int k = 0; k < 16; ++k) {
            float4 a0 = *(const float4*)&As[k][ty * 4];
            float4 a1 = *(const float4*)&As[k][64 + ty * 4];
            float4 b0 = *(const float4*)&Bs[k][tx * 4];
            float4 b1 = *(const float4*)&Bs[k][64 + tx * 4];
            float av[8] = {a0.x, a0.y, a0.z, a0.w, a1.x, a1.y, a1.z, a1.w};
            float bv[8] = {b0.x, b0.y, b0.z, b0.w, b1.x, b1.y, b1.z, b1.w};
#pragma unroll
            for (int i = 0; i < 8; ++i)
#pragma unroll
                for (int j = 0; j < 8; ++j)
                    acc[i][j] = fmaf(av[i], bv[j], acc[i][j]);
        }
        __syncthreads();
    }
#pragma unroll
    for (int ih = 0; ih < 2; ++ih)
#pragma unroll
        for (int i = 0; i < 4; ++i) {
            int row = row0 + ih * 64 + ty * 4 + i;
#pragma unroll
            for (int jh = 0; jh < 2; ++jh) {
                float4 v = make_float4(acc[ih * 4 + i][jh * 4 + 0], acc[ih * 4 + i][jh * 4 + 1],
                                       acc[ih * 4 + i][jh * 4 + 2], acc[ih * 4 + i][jh * 4 + 3]);
                *(float4*)&C[(size_t)row * ldc + col0 + jh * 64 + tx * 4] = v;
            }
        }
}

// ---------------- attention alpha prep over the whole half-batch ----------------

__global__ void k_attn_prep(const float* __restrict__ h, const float* __restrict__ a_src,
                            const float* __restrict__ a_dst,
                            float* __restrict__ asb, float* __restrict__ adb) {
    int idx = blockIdx.x * 256 + threadIdx.x;
    if (idx >= RB_ROWS * HEADS) return;
    int r = idx >> 2, hh = idx & 3;
    const float4* row = (const float4*)(h + (size_t)r * HC + hh * CDIM);
    const float4* av = (const float4*)(a_src + hh * CDIM);
    const float4* bv = (const float4*)(a_dst + hh * CDIM);
    float s1 = 0.f, s2 = 0.f;
#pragma unroll
    for (int c4 = 0; c4 < CDIM / 4; ++c4) {
        float4 v = row[c4], a = av[c4], b = bv[c4];
        s1 += v.x * a.x + v.y * a.y + v.z * a.z + v.w * a.w;
        s2 += v.x * b.x + v.y * b.y + v.z * b.z + v.w * b.w;
    }
    asb[idx] = s1;
    adb[idx] = s2;
}

// ---------------- GAT aggregation: 1 wave = 1 destination node ----------------
// lane = h*16 + c4 : head h, float4-group c4. Features slice-major [tl][node][HC].

template <bool CONCAT>
__global__ __launch_bounds__(256) void k_gat_agg(const float* __restrict__ hfeat,
                                                 const float* __restrict__ asb,
                                                 const float* __restrict__ adb,
                                                 const int* __restrict__ off_all,
                                                 const int* __restrict__ csr_all,
                                                 const float* __restrict__ bias,
                                                 float* __restrict__ out, int tbase) {
    const int tl = blockIdx.y;
    const int t = tbase + tl;
    const int wid = threadIdx.x >> 6;
    const int d = blockIdx.x * 4 + wid;
    const int lane = threadIdx.x & 63;
    const int h = lane >> 4;
    const int c4 = lane & 15;

    const int* off = off_all + (size_t)t * (N_NODES + 1);
    const int* csr = csr_all + (size_t)t * EPN + off[d];
    const int deg = off[d + 1] - off[d];
    const float* asl = asb + (size_t)tl * N_NODES * HEADS;
    const float adh = adb[((size_t)tl * N_NODES + d) * HEADS + h];

    // pass 1: per-head max (replicated across the head's 16 lanes)
    float m = -1e30f;
    for (int j = 0; j < deg; ++j) {
        int s = csr[j];
        float sc = asl[s * HEADS + h] + adh;
        sc = sc > 0.f ? sc : 0.2f * sc;
        m = fmaxf(m, sc);
    }

    // pass 2: weighted accumulate, float4 per lane
    const float4* feat = (const float4*)(hfeat + (size_t)tl * N_NODES * HC);
    float denom = 0.f;
    float ax = 0.f, ay = 0.f, az = 0.f, aw = 0.f;
    for (int j = 0; j < deg; ++j) {
        int s = csr[j];
        float sc = asl[s * HEADS + h] + adh;
        sc = sc > 0.f ? sc : 0.2f * sc;
        float w = expf(sc - m);
        denom += w;
        float4 v = feat[(size_t)s * (HC / 4) + lane];
        ax = fmaf(w, v.x, ax);
        ay = fmaf(w, v.y, ay);
        az = fmaf(w, v.z, az);
        aw = fmaf(w, v.w, aw);
    }
    float inv = 1.f / (denom + 1e-16f);
    ax *= inv; ay *= inv; az *= inv; aw *= inv;

    if (CONCAT) {
        float4 b = ((const float4*)bias)[lane];
        float4 o = make_float4(fmaxf(ax + b.x, 0.f), fmaxf(ay + b.y, 0.f),
                               fmaxf(az + b.z, 0.f), fmaxf(aw + b.w, 0.f));
        ((float4*)(out + ((size_t)tl * N_NODES + d) * HC))[lane] = o;
    } else {
        // mean over 4 heads: reduce across lane groups of 16
        ax += __shfl_xor(ax, 16, 64); ax += __shfl_xor(ax, 32, 64);
        ay += __shfl_xor(ay, 16, 64); ay += __shfl_xor(ay, 32, 64);
        az += __shfl_xor(az, 16, 64); az += __shfl_xor(az, 32, 64);
        aw += __shfl_xor(aw, 16, 64); aw += __shfl_xor(aw, 32, 64);
        if (h == 0) {
            float4 b = ((const float4*)bias)[c4];
            float4 o = make_float4(fmaxf(ax * 0.25f + b.x, 0.f), fmaxf(ay * 0.25f + b.y, 0.f),
                                   fmaxf(az * 0.25f + b.z, 0.f), fmaxf(aw * 0.25f + b.w, 0.f));
            ((float4*)(out + ((size_t)d * T_STEPS + t) * CDIM))[c4] = o;
        }
    }
}

// ---------------- persistent GRU over all 16 steps + final linear ----------------
// 1250 blocks x 192 threads, 16 nodes/block. g2_all layout: row(n,t) = n*T_STEPS + t.

__global__ __launch_bounds__(192) void k_gru_all(const float* __restrict__ g2_all,
                                                 const float* __restrict__ Wih,
                                                 const float* __restrict__ Whh,
                                                 const float* __restrict__ bih,
                                                 const float* __restrict__ bhh,
                                                 const float* __restrict__ Wout,
                                                 const float* __restrict__ bout,
                                                 float* __restrict__ out) {
    __shared__ float sA[16][64], sH[16][64];
    __shared__ float sGI[16][192], sGH[16][192];
    const int tid = threadIdx.x;
    const int node0 = blockIdx.x * 16;

    for (int idx = tid; idx < 16 * 64; idx += 192) {
        int n = idx >> 6, c = idx & 63;
        sH[n][c] = 0.f;
    }

    for (int t = 0; t < T_STEPS; ++t) {
        for (int idx = tid; idx < 16 * 64; idx += 192) {
            int n = idx >> 6, c = idx & 63;
            sA[n][c] = g2_all[((size_t)(node0 + n) * T_STEPS + t) * CDIM + c];
        }
        __syncthreads();
        float accI[16] = {}, accH[16] = {};
#pragma unroll 4
        for (int k = 0; k < 64; ++k) {
            float wi = Wih[k * G3 + tid];
            float wh = Whh[k * G3 + tid];
#pragma unroll
            for (int n = 0; n < 16; ++n) {
                accI[n] = fmaf(sA[n][k], wi, accI[n]);
                accH[n] = fmaf(sH[n][k], wh, accH[n]);
            }
        }
#pragma unroll
        for (int n = 0; n < 16; ++n) {
            sGI[n][tid] = accI[n];
            sGH[n][tid] = accH[n];
        }
        __syncthreads();
        for (int idx = tid; idx < 16 * 64; idx += 192) {
            int n = idx >> 6, c = idx & 63;
            float ir = sGI[n][c] + bih[c];
            float iz = sGI[n][64 + c] + bih[64 + c];
            float ig = sGI[n][128 + c] + bih[128 + c];
            float hr = sGH[n][c] + bhh[c];
            float hz = sGH[n][64 + c] + bhh[64 + c];
            float hg = sGH[n][128 + c] + bhh[128 + c];
            float r = 1.f / (1.f + expf(-(ir + hr)));
            float z = 1.f / (1.f + expf(-(iz + hz)));
            float g = tanhf(ig + r * hg);
            sH[n][c] = (1.f - z) * g + z * sH[n][c];
        }
        __syncthreads();
    }

    // final linear: out[n] = <h, Wout> + b
    for (int n = tid; n < 16; n += 192) {
        float s = 0.f;
#pragma unroll 8
        for (int c = 0; c < CDIM; ++c) s = fmaf(sH[n][c], Wout[c], s);
        out[node0 + n] = s + bout[0];
    }
}

// ---------------- launch ----------------

extern "C" void kernel_launch(void* const* d_in, const int* in_sizes, int n_in,
                              void* d_out, int out_size, void* d_ws, size_t ws_size,
                              hipStream_t stream) {
    const float* x   = (const float*)d_in[0];
    const int*   ei  = (const int*)d_in[1];
    const float* W1  = (const float*)d_in[2];
    const float* as1 = (const float*)d_in[3];
    const float* ad1 = (const float*)d_in[4];
    const float* b1  = (const float*)d_in[5];
    const float* W2  = (const float*)d_in[6];
    const float* as2 = (const float*)d_in[7];
    const float* ad2 = (const float*)d_in[8];
    const float* b2  = (const float*)d_in[9];
    const float* Wih = (const float*)d_in[10];
    const float* Whh = (const float*)d_in[11];
    const float* bih = (const float*)d_in[12];
    const float* bhh = (const float*)d_in[13];
    const float* Wout = (const float*)d_in[14];
    const float* bout = (const float*)d_in[15];

    float* ws = (float*)d_ws;
    float* h_half  = ws; ws += (size_t)RB_ROWS * HC;             // 163.8 MB
    float* g1_half = ws; ws += (size_t)RB_ROWS * HC;             // 163.8 MB
    float* g2_all  = ws; ws += (size_t)N_NODES * T_STEPS * CDIM; // 81.9 MB
    float* asb     = ws; ws += (size_t)RB_ROWS * HEADS;          // 2.56 MB
    float* adb     = ws; ws += (size_t)RB_ROWS * HEADS;          // 2.56 MB
    int* cnt_all = (int*)ws;
    int* cur_all = cnt_all + T_STEPS * N_NODES;
    int* off_all = cur_all + T_STEPS * N_NODES;
    int* csr_all = off_all + T_STEPS * (N_NODES + 1);

    dim3 thr(256);

    // CSR for all timesteps
    k_csr_init<<<(T_STEPS * N_NODES + 255) / 256, thr, 0, stream>>>(cnt_all);
    k_csr_count<<<dim3((N_EDGES + 255) / 256, T_STEPS), thr, 0, stream>>>(ei, cnt_all);
    k_csr_scan<<<T_STEPS, 1024, 0, stream>>>(cnt_all, off_all, cur_all);
    k_csr_fill<<<dim3((EPN + 255) / 256, T_STEPS), thr, 0, stream>>>(ei, cur_all, csr_all);

    for (int hb = 0; hb < 2; ++hb) {
        const int tbase = hb * TB;
        // GAT layer 1 over 8 timesteps at once
        k_gemm<true><<<dim3(2, RB_ROWS / 128), thr, 0, stream>>>(x, F_INDIM, W1, HC,
                                                                 h_half, HC, F_INDIM, tbase);
        k_attn_prep<<<(RB_ROWS * HEADS + 255) / 256, thr, 0, stream>>>(h_half, as1, ad1, asb, adb);
        k_gat_agg<true><<<dim3(N_NODES / 4, TB), thr, 0, stream>>>(h_half, asb, adb, off_all,
                                                                   csr_all, b1, g1_half, tbase);
        // GAT layer 2 (h_half reused as the pre-agg buffer)
        k_gemm<false><<<dim3(2, RB_ROWS / 128), thr, 0, stream>>>(g1_half, HC, W2, HC,
                                                                  h_half, HC, HC, tbase);
        k_attn_prep<<<(RB_ROWS * HEADS + 255) / 256, thr, 0, stream>>>(h_half, as2, ad2, asb, adb);
        k_gat_agg<false><<<dim3(N_NODES / 4, TB), thr, 0, stream>>>(h_half, asb, adb, off_all,
                                                                    csr_all, b2, g2_all, tbase);
    }

    k_gru_all<<<N_NODES / 16, 192, 0, stream>>>(g2_all, Wih, Whh, bih, bhh, Wout, bout,
                                                (float*)d_out);
}

// Round 4
// 3381.342 us; speedup vs baseline: 1.2776x; 1.2776x over previous
//
#include <hip/hip_runtime.h>
#include <math.h>

#define N_NODES 20000
#define N_EDGES 320000
#define T_STEPS 16
#define TB 8                       // timesteps per half-batch
#define RB_ROWS (N_NODES * TB)     // 160000 rows = 1250 * 128
#define F_INDIM 128
#define HC 256
#define HEADS 4
#define CDIM 64
#define G3 192
#define EPN (N_EDGES + N_NODES)    // 340000 edges incl self-loops per t

typedef __attribute__((ext_vector_type(8))) short bf16x8;
typedef __attribute__((ext_vector_type(8))) unsigned short ushort8;
typedef __attribute__((ext_vector_type(4))) float f32x4;

__device__ inline unsigned short f2bf(float x) {
    unsigned int u = __builtin_bit_cast(unsigned int, x);
    u += 0x7fffu + ((u >> 16) & 1u);
    return (unsigned short)(u >> 16);
}
__device__ inline void split_hilo(float x, unsigned short& h, unsigned short& l) {
    h = f2bf(x);
    float hf = __builtin_bit_cast(float, (unsigned int)h << 16);
    l = f2bf(x - hf);
}

// ---------------- conversions ----------------

// fp32 -> interleaved (hi,lo) bf16 pairs, 4 floats -> 8 ushorts per thread
__global__ void k_f2bf(const float* __restrict__ in, unsigned short* __restrict__ out, int n4) {
    int i = blockIdx.x * 256 + threadIdx.x;
    if (i >= n4) return;
    float4 v = ((const float4*)in)[i];
    ushort8 o;
    split_hilo(v.x, ((unsigned short*)&o)[0], ((unsigned short*)&o)[1]);
    split_hilo(v.y, ((unsigned short*)&o)[2], ((unsigned short*)&o)[3]);
    split_hilo(v.z, ((unsigned short*)&o)[4], ((unsigned short*)&o)[5]);
    split_hilo(v.w, ((unsigned short*)&o)[6], ((unsigned short*)&o)[7]);
    ((ushort8*)out)[i] = o;
}

// W[K][Ncol] fp32 -> Wt[Ncol][2K] bf16 hi/lo (transposed + split)
__global__ void k_wsplit(const float* __restrict__ W, unsigned short* __restrict__ Wt,
                         int K, int Ncol) {
    int idx = blockIdx.x * 256 + threadIdx.x;
    if (idx >= K * Ncol) return;
    int k = idx / Ncol, c = idx - k * Ncol;
    unsigned short h, l;
    split_hilo(W[idx], h, l);
    Wt[(size_t)c * 2 * K + 2 * k] = h;
    Wt[(size_t)c * 2 * K + 2 * k + 1] = l;
}

// ---------------- CSR build (all 16 timesteps in 4 launches) ----------------

__global__ void k_csr_init(int* __restrict__ cnt) {
    int i = blockIdx.x * 256 + threadIdx.x;
    if (i < T_STEPS * N_NODES) cnt[i] = 1;   // self-loop
}

__global__ void k_csr_count(const int* __restrict__ ei, int* __restrict__ cnt_all) {
    int t = blockIdx.y;
    int i = blockIdx.x * 256 + threadIdx.x;
    if (i < N_EDGES)
        atomicAdd(&cnt_all[t * N_NODES + ei[(size_t)t * 2 * N_EDGES + N_EDGES + i]], 1);
}

__global__ __launch_bounds__(1024) void k_csr_scan(const int* __restrict__ cnt_all,
                                                   int* __restrict__ off_all,
                                                   int* __restrict__ cur_all) {
    __shared__ int sdata[1024];
    const int t = blockIdx.x;
    const int* cnt = cnt_all + t * N_NODES;
    int* off = off_all + t * (N_NODES + 1);
    int* cur = cur_all + t * N_NODES;
    int tid = threadIdx.x;
    const int ITEMS = (N_NODES + 1023) / 1024;   // 20
    int start = tid * ITEMS;
    int local = 0;
    for (int i = 0; i < ITEMS; ++i) {
        int idx = start + i;
        if (idx < N_NODES) local += cnt[idx];
    }
    sdata[tid] = local;
    __syncthreads();
    for (int s = 1; s < 1024; s <<= 1) {
        int v = (tid >= s) ? sdata[tid - s] : 0;
        __syncthreads();
        sdata[tid] += v;
        __syncthreads();
    }
    int run = sdata[tid] - local;   // exclusive
    for (int i = 0; i < ITEMS; ++i) {
        int idx = start + i;
        if (idx < N_NODES) {
            off[idx] = run;
            cur[idx] = run;
            run += cnt[idx];
        }
    }
    if (tid == 0) off[N_NODES] = EPN;
}

__global__ void k_csr_fill(const int* __restrict__ ei, int* __restrict__ cur_all,
                           int* __restrict__ csr_all) {
    int t = blockIdx.y;
    int i = blockIdx.x * 256 + threadIdx.x;
    int* cur = cur_all + t * N_NODES;
    int* csr = csr_all + (size_t)t * EPN;
    const int* e = ei + (size_t)t * 2 * N_EDGES;
    if (i < N_EDGES) {
        int s = e[i], d = e[N_EDGES + i];
        csr[atomicAdd(&cur[d], 1)] = s;
    } else if (i < EPN) {
        int d = i - N_EDGES;
        csr[atomicAdd(&cur[d], 1)] = d;
    }
}

// ---------------- MFMA GEMM: C[rows x N] = A[rows x K2]bf16 * Bt[N x K2]bf16 ----------------
// BM=128, BN=64, 256 threads = 4 waves; wave w: rows [w*32, w*32+32), all 64 cols.
// K2 = bf16 element count along K (hi/lo interleaved), multiple of 32.

template <bool XMAP>
__global__ __launch_bounds__(256) void k_gemm_mfma(const unsigned short* __restrict__ A, int lda,
                                                   const unsigned short* __restrict__ Bt,
                                                   float* __restrict__ C, int ldc,
                                                   int K2, int tbase) {
    __shared__ unsigned short sA[128][40];
    __shared__ unsigned short sB[64][40];
    const int tid = threadIdx.x;
    const int wid = tid >> 6, lane = tid & 63;
    const int row0 = blockIdx.y * 128;
    const int col0 = blockIdx.x * 64;

    const int ar = tid >> 1, aq = (tid & 1) * 8;   // A stage: row, k-offset (elems)
    const int bc = tid >> 2, bq = (tid & 3) * 8;   // B stage: col, k-offset

    int l = row0 + ar;
    int rg;
    if (XMAP) { int tl = l / N_NODES; int s = l - tl * N_NODES; rg = s * T_STEPS + tbase + tl; }
    else rg = l;
    const unsigned short* Arow = A + (size_t)rg * lda;
    const unsigned short* Brow = Bt + (size_t)(col0 + bc) * K2;

    const int fr = lane & 15;   // fragment row (A) / col (B)
    const int kg = lane >> 4;   // k-group 0..3

    f32x4 acc[2][4] = {};

    for (int kk = 0; kk < K2; kk += 32) {
        ushort8 a0 = *(const ushort8*)(Arow + kk + aq);
        ushort8 a1 = *(const ushort8*)(Arow + kk + aq + 16);
        ushort8 b0 = *(const ushort8*)(Brow + kk + bq);
        *(ushort8*)&sA[ar][aq] = a0;
        *(ushort8*)&sA[ar][aq + 16] = a1;
        *(ushort8*)&sB[bc][bq] = b0;
        __syncthreads();
        bf16x8 af[2], bfv[4];
#pragma unroll
        for (int i = 0; i < 2; ++i)
            af[i] = *(const bf16x8*)&sA[wid * 32 + i * 16 + fr][kg * 8];
#pragma unroll
        for (int j = 0; j < 4; ++j)
            bfv[j] = *(const bf16x8*)&sB[j * 16 + fr][kg * 8];
#pragma unroll
        for (int i = 0; i < 2; ++i)
#pragma unroll
            for (int j = 0; j < 4; ++j)
                acc[i][j] = __builtin_amdgcn_mfma_f32_16x16x32_bf16(af[i], bfv[j], acc[i][j],
                                                                   0, 0, 0);
        __syncthreads();
    }
    // C/D layout: col = lane&15, row = (lane>>4)*4 + reg  [m89-verified]
#pragma unroll
    for (int i = 0; i < 2; ++i)
#pragma unroll
        for (int j = 0; j < 4; ++j) {
            int col = col0 + j * 16 + fr;
#pragma unroll
            for (int r = 0; r < 4; ++r) {
                int row = row0 + wid * 32 + i * 16 + kg * 4 + r;
                C[(size_t)row * ldc + col] = acc[i][j][r];
            }
        }
}

// ---------------- attention alpha prep ----------------

__global__ void k_attn_prep(const float* __restrict__ h, const float* __restrict__ a_src,
                            const float* __restrict__ a_dst,
                            float* __restrict__ asb, float* __restrict__ adb) {
    int idx = blockIdx.x * 256 + threadIdx.x;
    if (idx >= RB_ROWS * HEADS) return;
    int r = idx >> 2, hh = idx & 3;
    const float4* row = (const float4*)(h + (size_t)r * HC + hh * CDIM);
    const float4* av = (const float4*)(a_src + hh * CDIM);
    const float4* bv = (const float4*)(a_dst + hh * CDIM);
    float s1 = 0.f, s2 = 0.f;
#pragma unroll
    for (int c4 = 0; c4 < CDIM / 4; ++c4) {
        float4 v = row[c4], a = av[c4], b = bv[c4];
        s1 += v.x * a.x + v.y * a.y + v.z * a.z + v.w * a.w;
        s2 += v.x * b.x + v.y * b.y + v.z * b.z + v.w * b.w;
    }
    asb[idx] = s1;
    adb[idx] = s2;
}

// ---------------- GAT aggregation: 1 wave = 1 destination node ----------------
// lane = h*16 + c4. Features slice-major [tl][node][HC] fp32.
// Output written as interleaved bf16 hi/lo pairs (feeds the next MFMA GEMM).

template <bool CONCAT>
__global__ __launch_bounds__(256) void k_gat_agg(const float* __restrict__ hfeat,
                                                 const float* __restrict__ asb,
                                                 const float* __restrict__ adb,
                                                 const int* __restrict__ off_all,
                                                 const int* __restrict__ csr_all,
                                                 const float* __restrict__ bias,
                                                 unsigned short* __restrict__ out, int tbase) {
    const int tl = blockIdx.y;
    const int t = tbase + tl;
    const int wid = threadIdx.x >> 6;
    const int d = blockIdx.x * 4 + wid;
    const int lane = threadIdx.x & 63;
    const int h = lane >> 4;
    const int c4 = lane & 15;

    const int* off = off_all + (size_t)t * (N_NODES + 1);
    const int* csr = csr_all + (size_t)t * EPN + off[d];
    const int deg = off[d + 1] - off[d];
    const float* asl = asb + (size_t)tl * N_NODES * HEADS;
    const float adh = adb[((size_t)tl * N_NODES + d) * HEADS + h];

    // pass 1: per-head max (replicated across the head's 16 lanes)
    float m = -1e30f;
    for (int j = 0; j < deg; ++j) {
        int s = csr[j];
        float sc = asl[s * HEADS + h] + adh;
        sc = sc > 0.f ? sc : 0.2f * sc;
        m = fmaxf(m, sc);
    }

    // pass 2: weighted accumulate, float4 per lane
    const float4* feat = (const float4*)(hfeat + (size_t)tl * N_NODES * HC);
    float denom = 0.f;
    float ax = 0.f, ay = 0.f, az = 0.f, aw = 0.f;
    for (int j = 0; j < deg; ++j) {
        int s = csr[j];
        float sc = asl[s * HEADS + h] + adh;
        sc = sc > 0.f ? sc : 0.2f * sc;
        float w = expf(sc - m);
        denom += w;
        float4 v = feat[(size_t)s * (HC / 4) + lane];
        ax = fmaf(w, v.x, ax);
        ay = fmaf(w, v.y, ay);
        az = fmaf(w, v.z, az);
        aw = fmaf(w, v.w, aw);
    }
    float inv = 1.f / (denom + 1e-16f);
    ax *= inv; ay *= inv; az *= inv; aw *= inv;

    if (CONCAT) {
        float4 b = ((const float4*)bias)[lane];
        float v0 = fmaxf(ax + b.x, 0.f), v1 = fmaxf(ay + b.y, 0.f);
        float v2 = fmaxf(az + b.z, 0.f), v3 = fmaxf(aw + b.w, 0.f);
        ushort8 o;
        split_hilo(v0, ((unsigned short*)&o)[0], ((unsigned short*)&o)[1]);
        split_hilo(v1, ((unsigned short*)&o)[2], ((unsigned short*)&o)[3]);
        split_hilo(v2, ((unsigned short*)&o)[4], ((unsigned short*)&o)[5]);
        split_hilo(v3, ((unsigned short*)&o)[6], ((unsigned short*)&o)[7]);
        *(ushort8*)(out + ((size_t)tl * N_NODES + d) * (2 * HC) + lane * 8) = o;
    } else {
        // mean over 4 heads: reduce across lane groups of 16
        ax += __shfl_xor(ax, 16, 64); ax += __shfl_xor(ax, 32, 64);
        ay += __shfl_xor(ay, 16, 64); ay += __shfl_xor(ay, 32, 64);
        az += __shfl_xor(az, 16, 64); az += __shfl_xor(az, 32, 64);
        aw += __shfl_xor(aw, 16, 64); aw += __shfl_xor(aw, 32, 64);
        if (h == 0) {
            float4 b = ((const float4*)bias)[c4];
            float v0 = fmaxf(ax * 0.25f + b.x, 0.f), v1 = fmaxf(ay * 0.25f + b.y, 0.f);
            float v2 = fmaxf(az * 0.25f + b.z, 0.f), v3 = fmaxf(aw * 0.25f + b.w, 0.f);
            ushort8 o;
            split_hilo(v0, ((unsigned short*)&o)[0], ((unsigned short*)&o)[1]);
            split_hilo(v1, ((unsigned short*)&o)[2], ((unsigned short*)&o)[3]);
            split_hilo(v2, ((unsigned short*)&o)[4], ((unsigned short*)&o)[5]);
            split_hilo(v3, ((unsigned short*)&o)[6], ((unsigned short*)&o)[7]);
            *(ushort8*)(out + ((size_t)d * T_STEPS + t) * (2 * CDIM) + c4 * 8) = o;
        }
    }
}

// ---------------- persistent GRU (h-side GEMV only) + final linear ----------------
// 500 blocks x 512 threads (8 waves). Wave ng owns 5 nodes; lane = output channel c.
// Whh + H staged in LDS; zero barriers in the 16-step loop (sH rows are wave-private).

#define GRU_NPB 40
#define GRU_THREADS 512

__global__ __launch_bounds__(GRU_THREADS, 4) void k_gru_all(const float* __restrict__ GI,
                                                            const float* __restrict__ Whh,
                                                            const float* __restrict__ bih,
                                                            const float* __restrict__ bhh,
                                                            const float* __restrict__ Wout,
                                                            const float* __restrict__ bout,
                                                            float* __restrict__ out) {
    __shared__ float sW[64 * G3];        // Whh [k][col], 48 KB
    __shared__ float sH[GRU_NPB][68];    // padded rows
    const int tid = threadIdx.x;
    const int c = tid & 63;
    const int ng = tid >> 6;             // wave id 0..7
    const int n0 = ng * 5;
    const int nid0 = blockIdx.x * GRU_NPB + n0;

    for (int i = tid; i < 64 * G3; i += GRU_THREADS) sW[i] = Whh[i];
    for (int i = tid; i < GRU_NPB * 68; i += GRU_THREADS) ((float*)sH)[i] = 0.f;
    __syncthreads();

    const float bi0 = bih[c], bi1 = bih[64 + c], bi2 = bih[128 + c];
    const float bh0 = bhh[c], bh1 = bhh[64 + c], bh2 = bhh[128 + c];

    for (int t = 0; t < T_STEPS; ++t) {
        // prefetch GI for this step (hidden under the GEMV below)
        float gi0[5], gi1[5], gi2[5];
#pragma unroll
        for (int n = 0; n < 5; ++n) {
            const float* gp = GI + ((size_t)(nid0 + n) * T_STEPS + t) * G3;
            gi0[n] = gp[c]; gi1[n] = gp[64 + c]; gi2[n] = gp[128 + c];
        }
        float a0[5] = {}, a1[5] = {}, a2[5] = {};
        for (int k = 0; k < 64; k += 4) {
            f32x4 h4[5];
#pragma unroll
            for (int n = 0; n < 5; ++n) h4[n] = *(const f32x4*)&sH[n0 + n][k];
#pragma unroll
            for (int q = 0; q < 4; ++q) {
                float w0 = sW[(k + q) * G3 + c];
                float w1 = sW[(k + q) * G3 + 64 + c];
                float w2 = sW[(k + q) * G3 + 128 + c];
#pragma unroll
                for (int n = 0; n < 5; ++n) {
                    float hv = h4[n][q];
                    a0[n] = fmaf(hv, w0, a0[n]);
                    a1[n] = fmaf(hv, w1, a1[n]);
                    a2[n] = fmaf(hv, w2, a2[n]);
                }
            }
        }
#pragma unroll
        for (int n = 0; n < 5; ++n) {
            float r = 1.f / (1.f + expf(-(gi0[n] + bi0 + a0[n] + bh0)));
            float z = 1.f / (1.f + expf(-(gi1[n] + bi1 + a1[n] + bh1)));
            float g = tanhf(gi2[n] + bi2 + r * (a2[n] + bh2));
            sH[n0 + n][c] = (1.f - z) * g + z * sH[n0 + n][c];
        }
    }

    // final linear: out[n] = <h, Wout> + b  (wave butterfly reduce)
    float wc = Wout[c];
    float b0 = bout[0];
#pragma unroll
    for (int n = 0; n < 5; ++n) {
        float v = sH[n0 + n][c] * wc;
#pragma unroll
        for (int s = 32; s >= 1; s >>= 1) v += __shfl_xor(v, s, 64);
        if (c == 0) out[nid0 + n] = v + b0;
    }
}

// ---------------- launch ----------------

extern "C" void kernel_launch(void* const* d_in, const int* in_sizes, int n_in,
                              void* d_out, int out_size, void* d_ws, size_t ws_size,
                              hipStream_t stream) {
    const float* x   = (const float*)d_in[0];
    const int*   ei  = (const int*)d_in[1];
    const float* W1  = (const float*)d_in[2];
    const float* as1 = (const float*)d_in[3];
    const float* ad1 = (const float*)d_in[4];
    const float* b1  = (const float*)d_in[5];
    const float* W2  = (const float*)d_in[6];
    const float* as2 = (const float*)d_in[7];
    const float* ad2 = (const float*)d_in[8];
    const float* b2  = (const float*)d_in[9];
    const float* Wih = (const float*)d_in[10];
    const float* Whh = (const float*)d_in[11];
    const float* bih = (const float*)d_in[12];
    const float* bhh = (const float*)d_in[13];
    const float* Wout = (const float*)d_in[14];
    const float* bout = (const float*)d_in[15];

    float* ws = (float*)d_ws;
    float* h_half = ws;                                              // 160000*256 f32
    float* GI_all = ws;                                              // ALIAS over h_half+g1_bf
    unsigned short* g1_bf = (unsigned short*)(h_half + (size_t)RB_ROWS * HC);   // 160000*512 bf16
    unsigned short* g2_bf = g1_bf + (size_t)RB_ROWS * 2 * HC;        // 320000*128 bf16
    unsigned short* x_bf  = g2_bf + (size_t)N_NODES * T_STEPS * 2 * CDIM;  // 320000*256 bf16
    float* asb = (float*)(x_bf + (size_t)N_NODES * T_STEPS * 2 * F_INDIM);
    float* adb = asb + (size_t)RB_ROWS * HEADS;
    unsigned short* w1t  = (unsigned short*)(adb + (size_t)RB_ROWS * HEADS);  // 256 x 256
    unsigned short* w2t  = w1t + 256 * 256;                                   // 256 x 512
    unsigned short* wiht = w2t + 256 * 512;                                   // 192 x 128
    int* cnt_all = (int*)(wiht + 192 * 128);
    int* cur_all = cnt_all + T_STEPS * N_NODES;
    int* off_all = cur_all + T_STEPS * N_NODES;
    int* csr_all = off_all + T_STEPS * (N_NODES + 1);

    dim3 thr(256);

    // conversions
    k_f2bf<<<(N_NODES * T_STEPS * F_INDIM / 4 + 255) / 256, thr, 0, stream>>>(
        x, x_bf, N_NODES * T_STEPS * F_INDIM / 4);
    k_wsplit<<<(F_INDIM * HC + 255) / 256, thr, 0, stream>>>(W1, w1t, F_INDIM, HC);
    k_wsplit<<<(HC * HC + 255) / 256, thr, 0, stream>>>(W2, w2t, HC, HC);
    k_wsplit<<<(CDIM * G3 + 255) / 256, thr, 0, stream>>>(Wih, wiht, CDIM, G3);

    // CSR for all timesteps
    k_csr_init<<<(T_STEPS * N_NODES + 255) / 256, thr, 0, stream>>>(cnt_all);
    k_csr_count<<<dim3((N_EDGES + 255) / 256, T_STEPS), thr, 0, stream>>>(ei, cnt_all);
    k_csr_scan<<<T_STEPS, 1024, 0, stream>>>(cnt_all, off_all, cur_all);
    k_csr_fill<<<dim3((EPN + 255) / 256, T_STEPS), thr, 0, stream>>>(ei, cur_all, csr_all);

    for (int hb = 0; hb < 2; ++hb) {
        const int tbase = hb * TB;
        // GAT layer 1 over 8 timesteps at once
        k_gemm_mfma<true><<<dim3(4, RB_ROWS / 128), thr, 0, stream>>>(
            x_bf, 2 * F_INDIM, w1t, h_half, HC, 2 * F_INDIM, tbase);
        k_attn_prep<<<(RB_ROWS * HEADS + 255) / 256, thr, 0, stream>>>(h_half, as1, ad1, asb, adb);
        k_gat_agg<true><<<dim3(N_NODES / 4, TB), thr, 0, stream>>>(
            h_half, asb, adb, off_all, csr_all, b1, g1_bf, tbase);
        // GAT layer 2
        k_gemm_mfma<false><<<dim3(4, RB_ROWS / 128), thr, 0, stream>>>(
            g1_bf, 2 * HC, w2t, h_half, HC, 2 * HC, tbase);
        k_attn_prep<<<(RB_ROWS * HEADS + 255) / 256, thr, 0, stream>>>(h_half, as2, ad2, asb, adb);
        k_gat_agg<false><<<dim3(N_NODES / 4, TB), thr, 0, stream>>>(
            h_half, asb, adb, off_all, csr_all, b2, g2_bf, tbase);
    }

    // GI = g2 @ Wih for all (node, t) rows  (GI_all aliases dead h_half+g1_bf)
    k_gemm_mfma<false><<<dim3(3, N_NODES * T_STEPS / 128), thr, 0, stream>>>(
        g2_bf, 2 * CDIM, wiht, GI_all, G3, 2 * CDIM, 0);

    k_gru_all<<<N_NODES / GRU_NPB, GRU_THREADS, 0, stream>>>(GI_all, Whh, bih, bhh, Wout, bout,
                                                            (float*)d_out);
}